// Round 1
// baseline (466.300 us; speedup 1.0000x reference)
//
#include <hip/hip_runtime.h>

// Depthwise 1D cross-correlation, 13 taps (2K-1, K=7), zero-padded per row,
// kernel shared across all (b,c) rows. x: (32,512,4096) fp32 -> out same shape.
//
// out[row, l] = sum_{t=0}^{12} coef[t] * x[row, l + t - 6]
//   coef[t] = w[6-t] for t<=6 (reversed "previous" taps), w[t] for t>6.
//
// Memory-bound: 537 MB total traffic -> ~85 us floor at 6.3 TB/s.
//
// V2: no LDS, no barrier. Previous version staged each row in LDS with a
// HALO=6 offset -> scalar ds_write_b32 at 16B lane stride = 8-way bank
// conflict, plus a vmcnt(0)-draining __syncthreads between stage and compute.
// The reuse window is only 13 taps, so a register sliding window with direct
// global loads captures it; inter-thread halo overlap (each 64B line read by
// 3 adjacent threads) is an L1/L2 hit, not an HBM re-fetch.
//
// Layout: one block per row (4096 floats), 256 threads, each thread owns one
// 64B line: 16 consecutive outputs. Loads 8 aligned float4 (x[j-8..j+23],
// zero-guarded at row edges), 208 FMAs fully unrolled (all array indices
// compile-time), 4 float4 stores.

#define ROW_L 4096
#define TAPS 13
#define HALO 6
#define CHUNKS_PER_ROW 256   // 4096 / 16 floats per thread

__global__ __launch_bounds__(256) void conv13_direct_kernel(
    const float* __restrict__ x,
    const float* __restrict__ w,
    float* __restrict__ out)
{
    const int row = blockIdx.x;
    const int chunk = threadIdx.x;                       // 0..255
    const size_t base = (size_t)row * ROW_L + (size_t)chunk * 16;
    const float4* x4 = (const float4*)(x + base);        // 16B aligned
    float4* o4 = (float4*)(out + base);

    // Taps -> registers (uniform addresses -> s_load broadcast)
    float c[TAPS];
#pragma unroll
    for (int t = 0; t < TAPS; ++t)
        c[t] = (t <= HALO) ? w[HALO - t] : w[t];

    // Window x[base-8 .. base+23]; zero halo outside the row (also guards the
    // only truly OOB accesses at the global buffer edges).
    const float4 z4 = make_float4(0.f, 0.f, 0.f, 0.f);
    float4 rm2 = z4, rm1 = z4, rp4 = z4, rp5 = z4;
    if (chunk > 0)                   { rm2 = x4[-2]; rm1 = x4[-1]; }
    if (chunk < CHUNKS_PER_ROW - 1)  { rp4 = x4[4];  rp5 = x4[5]; }
    const float4 r0 = x4[0];
    const float4 r1 = x4[1];
    const float4 r2 = x4[2];
    const float4 r3 = x4[3];

    // in[k] = x[base - 6 + k], k = 0..27 (only .z/.w of rm2 and .x/.y of rp5
    // are live; compiler narrows those loads).
    const float in[28] = {
        rm2.z, rm2.w,
        rm1.x, rm1.y, rm1.z, rm1.w,
        r0.x, r0.y, r0.z, r0.w,
        r1.x, r1.y, r1.z, r1.w,
        r2.x, r2.y, r2.z, r2.w,
        r3.x, r3.y, r3.z, r3.w,
        rp4.x, rp4.y, rp4.z, rp4.w,
        rp5.x, rp5.y
    };

    float acc[16];
#pragma unroll
    for (int i = 0; i < 16; ++i) {
        float a = 0.f;
#pragma unroll
        for (int t = 0; t < TAPS; ++t)
            a = fmaf(c[t], in[i + t], a);   // x[base+i + t-6]
        acc[i] = a;
    }

#pragma unroll
    for (int g = 0; g < 4; ++g) {
        float4 o;
        o.x = acc[g * 4 + 0];
        o.y = acc[g * 4 + 1];
        o.z = acc[g * 4 + 2];
        o.w = acc[g * 4 + 3];
        o4[g] = o;
    }
}

extern "C" void kernel_launch(void* const* d_in, const int* in_sizes, int n_in,
                              void* d_out, int out_size, void* d_ws, size_t ws_size,
                              hipStream_t stream) {
    const float* x = (const float*)d_in[0];       // (32,512,4096) fp32
    const float* w = (const float*)d_in[1];       // (13,) fp32
    float* out = (float*)d_out;

    const int rows = in_sizes[0] / ROW_L;         // 32*512 = 16384
    conv13_direct_kernel<<<rows, 256, 0, stream>>>(x, w, out);
}